// Round 6
// baseline (294.205 us; speedup 1.0000x reference)
//
#include <hip/hip_runtime.h>

// MultiHeadAttention: BS=4, N=2048, D=512, H=8, DK=64. fp32 in/out, bf16 MFMA compute.
// Round 6: GEMM v2 (BK=64, A via global_load_lds, B=weights direct-from-global L2-hot
// register frags); attn v3 (gld16 staging into unpadded 64B-row chunked LDS, cheap bf16
// round). Bank pattern everywhere = stride-16-dword b128 (2-way, free per m136).

#define BS_    4
#define NSEQ   2048
#define DMODEL 512
#define NH     8
#define DKH    64
#define MROWS  (BS_ * NSEQ)   // 8192

typedef unsigned short ushort_t;
typedef __attribute__((ext_vector_type(8))) short short8;   // 8 bf16 (4 VGPRs)
typedef __attribute__((ext_vector_type(4))) float floatx4;  // 4 fp32 acc

__device__ __forceinline__ ushort_t f2bf(float f) {   // round-half-up, 2 VALU ops
    unsigned int x = __builtin_bit_cast(unsigned int, f);
    return (ushort_t)((x + 0x8000u) >> 16);
}
__device__ __forceinline__ floatx4 mfma_bf16(short8 a, short8 b, floatx4 c) {
    return __builtin_amdgcn_mfma_f32_16x16x32_bf16(a, b, c, 0, 0, 0);
}
__device__ __forceinline__ void gld16(const ushort_t* g, ushort_t* l) {
    __builtin_amdgcn_global_load_lds(
        (const __attribute__((address_space(1))) unsigned int*)g,
        (__attribute__((address_space(3))) unsigned int*)l, 16, 0, 0);
}

// ---------------- fp32 -> bf16 converts ----------------
__global__ __launch_bounds__(256) void cvt3_kernel(const float* __restrict__ a,
                                                   const float* __restrict__ b,
                                                   const float* __restrict__ c,
                                                   ushort_t* __restrict__ dst, int n4) {
    const float* src = (blockIdx.y == 0) ? a : (blockIdx.y == 1) ? b : c;
    ushort_t* d = dst + (size_t)blockIdx.y * ((size_t)n4 * 4);
    const int i = blockIdx.x * blockDim.x + threadIdx.x;
    const float4 v = ((const float4*)src)[i];
    ushort4 o;
    o.x = f2bf(v.x); o.y = f2bf(v.y); o.z = f2bf(v.z); o.w = f2bf(v.w);
    ((ushort4*)d)[i] = o;
}

__global__ __launch_bounds__(256) void cvt4_kernel(const float* __restrict__ a,
                                                   const float* __restrict__ b,
                                                   const float* __restrict__ c,
                                                   const float* __restrict__ e,
                                                   ushort_t* __restrict__ dst, int n4) {
    const float* src = (blockIdx.y == 0) ? a : (blockIdx.y == 1) ? b
                     : (blockIdx.y == 2) ? c : e;
    ushort_t* d = dst + (size_t)blockIdx.y * ((size_t)n4 * 4);
    const int i = blockIdx.x * blockDim.x + threadIdx.x;
    const float4 v = ((const float4*)src)[i];
    ushort4 o;
    o.x = f2bf(v.x); o.y = f2bf(v.y); o.z = f2bf(v.z); o.w = f2bf(v.w);
    ((ushort4*)d)[i] = o;
}

// ---------------- fused projection GEMM v2 (Q/K/V via blockIdx.z) ----------------
// C[m][d] = rowmask[m] * sum_k X[m][k] * W[d][k].  BK=64; A staged via gld16 into
// chunked LDS; B-frags direct from global (W is L2-resident, shared by all blocks).
__global__ __launch_bounds__(256) void gemm_proj(const ushort_t* __restrict__ Xall,
                                                 const ushort_t* __restrict__ Wall,
                                                 const float* __restrict__ qmas,
                                                 const float* __restrict__ kmas,
                                                 ushort_t* __restrict__ Qh,
                                                 ushort_t* __restrict__ Kh,
                                                 ushort_t* __restrict__ Vt) {
    __shared__ ushort_t As[2][128 * 32];   // chunk h = k-cols [k0+h*32, +32)
    const int z = blockIdx.z;
    const ushort_t* X  = Xall + (size_t)z * MROWS * DMODEL;
    const ushort_t* Wb = Wall + (size_t)z * DMODEL * DMODEL;
    const float* rowmask = (z == 0) ? qmas : kmas;

    const int tid  = threadIdx.x;
    const int wave = tid >> 6;
    const int lane = tid & 63;
    const int l16  = lane & 15;
    const int quad = lane >> 4;
    const int wr   = wave >> 1;
    const int wc   = wave & 1;
    const int m0   = blockIdx.x * 128;
    const int n0   = blockIdx.y * 128;
    const int r4   = lane >> 2;
    const int p4   = lane & 3;

    floatx4 acc[4][4];
#pragma unroll
    for (int t = 0; t < 4; ++t)
#pragma unroll
        for (int u = 0; u < 4; ++u) acc[t][u] = (floatx4){0.f, 0.f, 0.f, 0.f};

    const ushort_t* Wrow[4];
#pragma unroll
    for (int u = 0; u < 4; ++u)
        Wrow[u] = Wb + (size_t)(n0 + wc * 64 + u * 16 + l16) * DMODEL + quad * 8;

    for (int k0 = 0; k0 < DMODEL; k0 += 64) {
#pragma unroll
        for (int i = 0; i < 4; ++i) {
            const int idx = wave * 4 + i;
            const int h = idx >> 3, rg = idx & 7;
            gld16(X + (size_t)(m0 + rg * 16 + r4) * DMODEL + k0 + h * 32 + p4 * 8,
                  &As[h][rg * 512]);
        }
        short8 bf[4][2];
#pragma unroll
        for (int u = 0; u < 4; ++u)
#pragma unroll
            for (int kc = 0; kc < 2; ++kc)
                bf[u][kc] = *(const short8*)(Wrow[u] + k0 + kc * 32);
        __syncthreads();
        short8 af[4][2];
#pragma unroll
        for (int t = 0; t < 4; ++t)
#pragma unroll
            for (int kc = 0; kc < 2; ++kc)
                af[t][kc] = *(const short8*)&As[kc][(wr * 64 + t * 16 + l16) * 32 + quad * 8];
#pragma unroll
        for (int t = 0; t < 4; ++t)
#pragma unroll
            for (int u = 0; u < 4; ++u) {
                acc[t][u] = mfma_bf16(af[t][0], bf[u][0], acc[t][u]);
                acc[t][u] = mfma_bf16(af[t][1], bf[u][1], acc[t][u]);
            }
        __syncthreads();
    }

    float rm[4][4];
#pragma unroll
    for (int t = 0; t < 4; ++t)
#pragma unroll
        for (int r = 0; r < 4; ++r)
            rm[t][r] = rowmask[m0 + wr * 64 + t * 16 + quad * 4 + r];

    const int bb    = m0 >> 11;
    const int nbase = (m0 & (NSEQ - 1)) + wr * 64;
#pragma unroll
    for (int t = 0; t < 4; ++t) {
#pragma unroll
        for (int u = 0; u < 4; ++u) {
            const int d = n0 + wc * 64 + u * 16 + l16;
            const int h = d >> 6, cc = d & 63;
            if (z < 2) {
                ushort_t* dst = (z == 0) ? Qh : Kh;
#pragma unroll
                for (int r = 0; r < 4; ++r) {
                    const int n = nbase + t * 16 + quad * 4 + r;
                    dst[((size_t)(bb * NH + h) * NSEQ + n) * DKH + cc] =
                        f2bf(acc[t][u][r] * rm[t][r]);
                }
            } else {
                ushort4 pk;
                pk.x = f2bf(acc[t][u][0] * rm[t][0]);
                pk.y = f2bf(acc[t][u][1] * rm[t][1]);
                pk.z = f2bf(acc[t][u][2] * rm[t][2]);
                pk.w = f2bf(acc[t][u][3] * rm[t][3]);
                const int n = nbase + t * 16 + quad * 4;
                *(ushort4*)(Vt + ((size_t)(bb * NH + h) * DKH + cc) * NSEQ + n) = pk;
            }
        }
    }
}

// ---------------- output GEMM v2 ----------------
__global__ __launch_bounds__(256) void gemm_out(const ushort_t* __restrict__ X,
                                                const ushort_t* __restrict__ Wb,
                                                const float* __restrict__ rowmask,
                                                float* __restrict__ dst) {
    __shared__ ushort_t As[2][128 * 32];
    const int tid  = threadIdx.x;
    const int wave = tid >> 6;
    const int lane = tid & 63;
    const int l16  = lane & 15;
    const int quad = lane >> 4;
    const int wr   = wave >> 1;
    const int wc   = wave & 1;
    const int m0   = blockIdx.x * 128;
    const int n0   = blockIdx.y * 128;
    const int r4   = lane >> 2;
    const int p4   = lane & 3;

    floatx4 acc[4][4];
#pragma unroll
    for (int t = 0; t < 4; ++t)
#pragma unroll
        for (int u = 0; u < 4; ++u) acc[t][u] = (floatx4){0.f, 0.f, 0.f, 0.f};

    const ushort_t* Wrow[4];
#pragma unroll
    for (int u = 0; u < 4; ++u)
        Wrow[u] = Wb + (size_t)(n0 + wc * 64 + u * 16 + l16) * DMODEL + quad * 8;

    for (int k0 = 0; k0 < DMODEL; k0 += 64) {
#pragma unroll
        for (int i = 0; i < 4; ++i) {
            const int idx = wave * 4 + i;
            const int h = idx >> 3, rg = idx & 7;
            gld16(X + (size_t)(m0 + rg * 16 + r4) * DMODEL + k0 + h * 32 + p4 * 8,
                  &As[h][rg * 512]);
        }
        short8 bf[4][2];
#pragma unroll
        for (int u = 0; u < 4; ++u)
#pragma unroll
            for (int kc = 0; kc < 2; ++kc)
                bf[u][kc] = *(const short8*)(Wrow[u] + k0 + kc * 32);
        __syncthreads();
        short8 af[4][2];
#pragma unroll
        for (int t = 0; t < 4; ++t)
#pragma unroll
            for (int kc = 0; kc < 2; ++kc)
                af[t][kc] = *(const short8*)&As[kc][(wr * 64 + t * 16 + l16) * 32 + quad * 8];
#pragma unroll
        for (int t = 0; t < 4; ++t)
#pragma unroll
            for (int u = 0; u < 4; ++u) {
                acc[t][u] = mfma_bf16(af[t][0], bf[u][0], acc[t][u]);
                acc[t][u] = mfma_bf16(af[t][1], bf[u][1], acc[t][u]);
            }
        __syncthreads();
    }

#pragma unroll
    for (int t = 0; t < 4; ++t) {
#pragma unroll
        for (int r = 0; r < 4; ++r) {
            const int m = m0 + wr * 64 + t * 16 + quad * 4 + r;
            const float rm = rowmask[m];
#pragma unroll
            for (int u = 0; u < 4; ++u) {
                const int d = n0 + wc * 64 + u * 16 + l16;
                dst[(size_t)m * DMODEL + d] = acc[t][u][r] * rm;
            }
        }
    }
}

// ---------------- flash attention v3 ----------------
// Qh, Kh: [b][h][n][64] bf16;  Vt: [b][h][c][n] bf16;  amas/kmas fp32; y bf16.
// 64-q blocks (4 waves x 16 q), 128-key tiles via gld16 into chunked 64B-row LDS.
__global__ __launch_bounds__(256, 3) void attn_kernel(const ushort_t* __restrict__ Qh,
                                                      const ushort_t* __restrict__ Kh,
                                                      const ushort_t* __restrict__ Vt,
                                                      const float* __restrict__ amas,
                                                      const float* __restrict__ kmas,
                                                      ushort_t* __restrict__ y) {
    __shared__ ushort_t Ks[2][128 * 32];    // chunk h: K c-cols [h*32,+32), row=key
    __shared__ ushort_t Vs[4][64 * 32];     // chunk kf: keys [kf*32,+32), row=c
    __shared__ ushort_t Ps[4][4][16 * 32];  // [wave][kf][q*32 + key-in-chunk]

    const int tid  = threadIdx.x;
    const int wave = tid >> 6;
    const int lane = tid & 63;
    const int l16  = lane & 15;
    const int quad = lane >> 4;
    const int r4   = lane >> 2;
    const int p4   = lane & 3;
    const int h    = blockIdx.y;
    const int b    = blockIdx.z;
    const int qw   = blockIdx.x * 64 + wave * 16;   // this wave's 16 q-rows

    const ushort_t* Kb = Kh + (size_t)(b * NH + h) * NSEQ * DKH;
    const ushort_t* Vb = Vt + (size_t)(b * NH + h) * DKH * NSEQ;
    const float*    Am = amas + (size_t)(b * NSEQ + qw) * NSEQ;

    const ushort_t* Qp = Qh + ((size_t)((b * NH + h) * NSEQ) + qw + l16) * DKH + quad * 8;
    const short8 qfa = *(const short8*)Qp;
    const short8 qfb = *(const short8*)(Qp + 32);

    float lpart[4] = {0.f, 0.f, 0.f, 0.f};
    floatx4 accO[4];
#pragma unroll
    for (int ct = 0; ct < 4; ++ct) accO[ct] = (floatx4){0.f, 0.f, 0.f, 0.f};

    const float CEXP = 0.18033688011112042f;  // log2(e)/8

    for (int kt = 0; kt < NSEQ / 128; ++kt) {
        const int k0 = kt * 128;

        __syncthreads();   // previous tile's LDS reads complete (WAR)

        // ---- amas for this tile (drains under the same barrier as staging) ----
        float av[8][4];
#pragma unroll
        for (int fr = 0; fr < 8; ++fr)
#pragma unroll
            for (int r = 0; r < 4; ++r)
                av[fr][r] = Am[(size_t)(quad * 4 + r) * NSEQ + k0 + fr * 16 + l16];

        // ---- async stage K (16 KB) and V (16 KB) ----
#pragma unroll
        for (int i = 0; i < 4; ++i) {
            const int idx = wave * 4 + i;
            const int hh = idx >> 3, rg = idx & 7;
            gld16(Kb + (size_t)(k0 + rg * 16 + r4) * DKH + hh * 32 + p4 * 8,
                  &Ks[hh][rg * 512]);
        }
#pragma unroll
        for (int i = 0; i < 4; ++i) {
            const int idx = wave * 4 + i;
            const int kf = idx >> 2, rg = idx & 3;
            gld16(Vb + (size_t)(rg * 16 + r4) * NSEQ + k0 + kf * 32 + p4 * 8,
                  &Vs[kf][rg * 512]);
        }
        __syncthreads();   // tile staged

        // ---- S = Q.K^T (16 q x 128 keys) ----
        floatx4 S[8];
#pragma unroll
        for (int fr = 0; fr < 8; ++fr) {
            const short8 ka = *(const short8*)&Ks[0][(fr * 16 + l16) * 32 + quad * 8];
            const short8 kb = *(const short8*)&Ks[1][(fr * 16 + l16) * 32 + quad * 8];
            floatx4 s = {0.f, 0.f, 0.f, 0.f};
            s = mfma_bf16(qfa, ka, s);
            s = mfma_bf16(qfb, kb, s);
            S[fr] = s;
        }

        // ---- masked no-max softmax numerator; P -> wave-private chunked LDS ----
#pragma unroll
        for (int fr = 0; fr < 8; ++fr) {
#pragma unroll
            for (int r = 0; r < 4; ++r) {
                const float p = av[fr][r] * exp2f(S[fr][r] * CEXP);
                lpart[r] += p;
                Ps[wave][fr >> 1][(quad * 4 + r) * 32 + (fr & 1) * 16 + l16] = f2bf(p);
            }
        }

        __builtin_amdgcn_wave_barrier();  // LDS W->R order (wave-local, in-order DS pipe)
        short8 pf[4];
#pragma unroll
        for (int kf = 0; kf < 4; ++kf)
            pf[kf] = *(const short8*)&Ps[wave][kf][l16 * 32 + quad * 8];
        __builtin_amdgcn_wave_barrier();

        // ---- O += P.V ----
#pragma unroll
        for (int ct = 0; ct < 4; ++ct) {
#pragma unroll
            for (int kf = 0; kf < 4; ++kf) {
                const short8 vb = *(const short8*)&Vs[kf][(ct * 16 + l16) * 32 + quad * 8];
                accO[ct] = mfma_bf16(pf[kf], vb, accO[ct]);
            }
        }
    }

    // ---- epilogue: normalize by l, post-mask, store ----
#pragma unroll
    for (int r = 0; r < 4; ++r) {
        float l = lpart[r];
        l += __shfl_xor(l, 1);
        l += __shfl_xor(l, 2);
        l += __shfl_xor(l, 4);
        l += __shfl_xor(l, 8);
        const int q = qw + quad * 4 + r;
        const float scale = kmas[b * NSEQ + q] / l;
#pragma unroll
        for (int ct = 0; ct < 4; ++ct) {
            y[(size_t)(b * NSEQ + q) * DMODEL + h * DKH + ct * 16 + l16] =
                f2bf(accO[ct][r] * scale);
        }
    }
}

extern "C" void kernel_launch(void* const* d_in, const int* in_sizes, int n_in,
                              void* d_out, int out_size, void* d_ws, size_t ws_size,
                              hipStream_t stream) {
    (void)in_sizes; (void)n_in; (void)out_size; (void)ws_size;
    const float* Q  = (const float*)d_in[0];
    const float* K  = (const float*)d_in[1];
    const float* V  = (const float*)d_in[2];
    const float* qm = (const float*)d_in[3];
    const float* km = (const float*)d_in[4];
    const float* am = (const float*)d_in[5];
    const float* WQ = (const float*)d_in[6];
    const float* WK = (const float*)d_in[7];
    const float* WV = (const float*)d_in[8];
    const float* WO = (const float*)d_in[9];

    const size_t XN = (size_t)MROWS * DMODEL;        // 4,194,304
    const size_t WN = (size_t)DMODEL * DMODEL;       // 262,144
    ushort_t* Xbf = (ushort_t*)d_ws;                 // Q,K,V bf16: 3*XN
    ushort_t* Wbf = Xbf + 3 * XN;                    // WQ,WK,WV,WO bf16: 4*WN
    ushort_t* WOb = Wbf + 3 * WN;
    ushort_t* Qh  = Wbf + 4 * WN;
    ushort_t* Kh  = Qh + XN;
    ushort_t* Vt  = Kh + XN;
    ushort_t* y   = Vt + XN;
    float* out = (float*)d_out;

    hipLaunchKernelGGL(cvt3_kernel, dim3(4096, 3), dim3(256), 0, stream,
                       Q, K, V, Xbf, (int)(XN / 4));
    hipLaunchKernelGGL(cvt4_kernel, dim3(256, 4), dim3(256), 0, stream,
                       WQ, WK, WV, WO, Wbf, (int)(WN / 4));

    hipLaunchKernelGGL(gemm_proj, dim3(MROWS / 128, DMODEL / 128, 3), dim3(256), 0, stream,
                       Xbf, Wbf, qm, km, Qh, Kh, Vt);

    hipLaunchKernelGGL(attn_kernel, dim3(NSEQ / 64, NH, BS_), dim3(256), 0, stream,
                       Qh, Kh, Vt, am, km, y);

    hipLaunchKernelGGL(gemm_out, dim3(MROWS / 128, DMODEL / 128), dim3(256), 0, stream,
                       y, WOb, km, out);
}